// Round 12
// baseline (808.167 us; speedup 1.0000x reference)
//
#include <hip/hip_runtime.h>
#include <cstdint>
#include <cstddef>

// ---------------- constants ----------------
static constexpr int F      = 6912;          // C*S*S
static constexpr int BATCH  = 64;
static constexpr size_t NF  = (size_t)BATCH * F;   // 442368
static constexpr int BKT    = 64;            // k per LDS stage
static constexpr int NT     = F / BKT;       // 108 k-stages total
static constexpr int NTH    = NT / 2;        // 54 per wave-group
static constexpr int NT2    = F / 32;        // 216 n-tiles (n=32)
static constexpr int DEPTH  = 6;             // LDS ring buffers per group (= PREF+2)
static constexpr int PREF   = 4;             // stages prefetched ahead
static constexpr int STAGE_B = 12288;        // bytes per stage: A 8KB + B 4KB
static constexpr int STAGE_U = STAGE_B / 2;  // in ushorts
static constexpr size_t GEMM_LDS = 2 * (size_t)DEPTH * STAGE_B + 1024;  // 148480

typedef short bf16x8 __attribute__((ext_vector_type(8)));
typedef float f32x4  __attribute__((ext_vector_type(4)));
typedef unsigned short ushort_t;

__device__ __forceinline__ unsigned short f2bf(float f) {
    union { float f; uint32_t u; } x; x.f = f;
    uint32_t r = x.u + 0x7fffu + ((x.u >> 16) & 1u);
    return (unsigned short)(r >> 16);
}

#define GLOAD_LDS16(gp, lp) \
    __builtin_amdgcn_global_load_lds((const __attribute__((address_space(1))) void*)(gp), \
                                     (__attribute__((address_space(3))) void*)(lp), 16, 0, 0)

// ---------------- panel layout ----------------
// EP[((nt*108 + k0t)*32 + n%32)*64 + k%64] (bf16); one (nt,k0t) chunk = 4KB contiguous.
// EP1(n,k) = E[n][k]; EP2(n,k) = E[k][n].

// ---------------- build: K -> EP1, EP2 (E = K - I, bf16) ----------------
__global__ __launch_bounds__(256) void build_ep3(
    const float* __restrict__ K0, const float* __restrict__ K1, const float* __restrict__ K2,
    ushort_t* __restrict__ P10, ushort_t* __restrict__ P20,
    ushort_t* __restrict__ P11, ushort_t* __restrict__ P21,
    ushort_t* __restrict__ P12, ushort_t* __restrict__ P22) {
    __shared__ float tile[64][65];
    int z = blockIdx.z;
    const float* K = (z == 0) ? K0 : (z == 1) ? K1 : K2;
    ushort_t* P1 = (z == 0) ? P10 : (z == 1) ? P11 : P12;
    ushort_t* P2 = (z == 0) ? P20 : (z == 1) ? P21 : P22;
    int bj = blockIdx.x * 64;       // col tile (fast dim -> streaming reads)
    int bi = blockIdx.y * 64;       // row tile
    int t = threadIdx.x;
    int r = t >> 2, c0 = (t & 3) * 16;
    const float4* src = reinterpret_cast<const float4*>(K + (size_t)(bi + r) * F + bj + c0);
    float4 v0 = src[0], v1 = src[1], v2 = src[2], v3 = src[3];
    float vv[16] = {v0.x,v0.y,v0.z,v0.w, v1.x,v1.y,v1.z,v1.w,
                    v2.x,v2.y,v2.z,v2.w, v3.x,v3.y,v3.z,v3.w};
#pragma unroll
    for (int e = 0; e < 16; ++e) {
        float f = vv[e];
        if (bi + r == bj + c0 + e) f -= 1.0f;
        tile[r][c0 + e] = f;
    }
    __syncthreads();
    // EP1: n = bi+rq, k = bj + c8*8+e
#pragma unroll
    for (int i = 0; i < 2; ++i) {
        int g = t + i * 256;
        int rq = g >> 3, c8 = g & 7;
        ushort_t pk[8];
#pragma unroll
        for (int e = 0; e < 8; ++e) pk[e] = f2bf(tile[rq][c8 * 8 + e]);
        size_t nt = (size_t)((bi + rq) >> 5);
        size_t dst = ((nt * 108 + (bj >> 6)) * 32 + (rq & 31)) * 64 + c8 * 8;
        *reinterpret_cast<uint4*>(P1 + dst) = *reinterpret_cast<uint4*>(pk);
    }
    // EP2: n = bj+rq, k = bi + c8*8+e  (transposed LDS read)
#pragma unroll
    for (int i = 0; i < 2; ++i) {
        int g = t + i * 256;
        int rq = g >> 3, c8 = g & 7;
        ushort_t pk[8];
#pragma unroll
        for (int e = 0; e < 8; ++e) pk[e] = f2bf(tile[c8 * 8 + e][rq]);
        size_t nt = (size_t)((bj + rq) >> 5);
        size_t dst = ((nt * 108 + (bi >> 6)) * 32 + (rq & 31)) * 64 + c8 * 8;
        *reinterpret_cast<uint4*>(P2 + dst) = *reinterpret_cast<uint4*>(pk);
    }
}

// ---------------- fused skinny GEMM (M=64, n-tile=32, 512 thr, in-block K-split) ----------
// Merged dispatch: blockIdx.y selects chain {0,1}, each with its own arg set.
__device__ __forceinline__ void issue_stage(const ushort_t* __restrict__ Abf,
                                            const ushort_t* __restrict__ EP,
                                            ushort_t* ring, int sidx,
                                            int nt_blk, int kt, int wl, int l) {
    int k0 = kt * BKT;
    ushort_t* bufA = ring + sidx * STAGE_U;
    ushort_t* bufB = bufA + 4096;
    // A: 64 rows x 64 k bf16, XOR-swizzled granules (2 issues/thread)
#pragma unroll
    for (int i = 0; i < 2; ++i) {
        int slot = wl * 128 + i * 64 + l;
        int row = slot >> 3;
        int cs16 = (slot & 7) ^ (row & 7);
        GLOAD_LDS16(Abf + (size_t)row * F + k0 + cs16 * 8, bufA + (wl * 128 + i * 64) * 8);
    }
    // B: one 4KB contiguous panel chunk; XOR swizzle folded into source offset
    {
        const ushort_t* bbase = EP + ((size_t)nt_blk * 108 + kt) * 2048;
        int slot = wl * 64 + l;
        int row = slot >> 3;
        int cs16 = (slot & 7) ^ (row & 7);
        GLOAD_LDS16(bbase + row * 64 + cs16 * 8, bufB + (wl * 64) * 8);
    }
}

__device__ __forceinline__ void compute_stage(const ushort_t* ring, int sidx,
                                              f32x4 acc[2], int wl, int l) {
    const char* base = (const char*)(ring + sidx * STAGE_U);
    int lrow = l & 15, lq = l >> 4;
    int arow = wl * 16 + lrow;
#pragma unroll
    for (int ks = 0; ks < 2; ++ks) {
        int acol = ((ks * 4 + lq) ^ (arow & 7)) * 16;
        bf16x8 af = *(const bf16x8*)(base + arow * 128 + acol);
#pragma unroll
        for (int j = 0; j < 2; ++j) {
            int brow = j * 16 + lrow;
            int bcol = ((ks * 4 + lq) ^ (brow & 7)) * 16;
            bf16x8 bf = *(const bf16x8*)(base + 8192 + brow * 128 + bcol);
            acc[j] = __builtin_amdgcn_mfma_f32_16x16x32_bf16(af, bf, acc[j], 0, 0, 0);
        }
    }
}

template<int MODE>
__global__ __launch_bounds__(512) void gemm_fused(
    const ushort_t* __restrict__ Abf0, const ushort_t* __restrict__ EP0,
    const float* __restrict__ base0, const float* __restrict__ sin0,
    const float* __restrict__ g0, const float* __restrict__ bt0, float sc0,
    float* __restrict__ of0, ushort_t* __restrict__ ob0,
    const ushort_t* __restrict__ Abf1, const ushort_t* __restrict__ EP1c,
    const float* __restrict__ base1, const float* __restrict__ sin1,
    const float* __restrict__ g1, const float* __restrict__ bt1, float sc1,
    float* __restrict__ of1, ushort_t* __restrict__ ob1)
{
    extern __shared__ __align__(16) char smem[];
    ushort_t* stage = (ushort_t*)smem;                                 // 2 rings
    float* redS = (float*)(smem + 2 * DEPTH * STAGE_B);
    float* redQ = redS + 128;

    int chain = blockIdx.y;
    const ushort_t* Abf    = chain ? Abf1 : Abf0;
    const ushort_t* EP     = chain ? EP1c : EP0;
    const float* base_f32  = chain ? base1 : base0;
    const float* s_in      = chain ? sin1 : sin0;
    const float* gamma     = chain ? g1 : g0;
    const float* beta      = chain ? bt1 : bt0;
    float scale            = chain ? sc1 : sc0;
    float* out_f32         = chain ? of1 : of0;
    ushort_t* out_bf       = chain ? ob1 : ob0;

    int nt_blk = blockIdx.x;
    int n0 = nt_blk * 32;
    int tid = threadIdx.x;
    int w = tid >> 6, l = tid & 63;
    int wl = w & 3;                 // wave within group
    int g  = w >> 2;                // k-group 0/1
    ushort_t* ring = stage + g * (DEPTH * STAGE_U);
    int kbase = g * NTH;

    f32x4 acc[2];
    acc[0] = (f32x4)0.0f; acc[1] = (f32x4)0.0f;

#pragma unroll
    for (int t = 0; t < PREF; ++t) issue_stage(Abf, EP, ring, t, nt_blk, kbase + t, wl, l);

    for (int t = 0; t < NTH; ++t) {
        if (t + PREF < NTH) issue_stage(Abf, EP, ring, (t + PREF) % DEPTH, nt_blk, kbase + t + PREF, wl, l);
        int ahead = NTH - 1 - t; if (ahead > PREF) ahead = PREF;
        if (ahead >= 4)      asm volatile("s_waitcnt vmcnt(12)" ::: "memory");
        else if (ahead == 3) asm volatile("s_waitcnt vmcnt(9)"  ::: "memory");
        else if (ahead == 2) asm volatile("s_waitcnt vmcnt(6)"  ::: "memory");
        else if (ahead == 1) asm volatile("s_waitcnt vmcnt(3)"  ::: "memory");
        else                 asm volatile("s_waitcnt vmcnt(0)"  ::: "memory");
        __builtin_amdgcn_s_barrier();
        asm volatile("" ::: "memory");
        compute_stage(ring, t % DEPTH, acc, wl, l);
    }

    // ---- cross-group K reduction (group 1 -> group 0) via reused ring LDS ----
    __syncthreads();
    float* accx = (float*)smem;
    if (w >= 4) {
        int base = ((w - 4) * 64 + l) * 8;
#pragma unroll
        for (int r = 0; r < 4; ++r) { accx[base + r] = acc[0][r]; accx[base + 4 + r] = acc[1][r]; }
    }
    __syncthreads();
    if (w < 4) {
        int base = (w * 64 + l) * 8;
#pragma unroll
        for (int r = 0; r < 4; ++r) { acc[0][r] += accx[base + r]; acc[1][r] += accx[base + 4 + r]; }
    }

    int lrow = l & 15, lq = l >> 4;
    if (MODE == 0) {
        float v[2][4];
        if (w < 4) {
#pragma unroll
            for (int j = 0; j < 2; ++j)
#pragma unroll
                for (int r = 0; r < 4; ++r) {
                    int m = w * 16 + lq * 4 + r;
                    int n = n0 + j * 16 + lrow;
                    v[j][r] = acc[j][r] + base_f32[(size_t)m * F + n];
                }
#pragma unroll
            for (int j = 0; j < 2; ++j) {
                float ps = v[j][0] + v[j][1] + v[j][2] + v[j][3];
                float pq = v[j][0]*v[j][0] + v[j][1]*v[j][1] + v[j][2]*v[j][2] + v[j][3]*v[j][3];
                ps += __shfl_xor(ps, 16); pq += __shfl_xor(pq, 16);
                ps += __shfl_xor(ps, 32); pq += __shfl_xor(pq, 32);
                if (lq == 0) { redS[(w * 2 + j) * 16 + lrow] = ps; redQ[(w * 2 + j) * 16 + lrow] = pq; }
            }
        }
        __syncthreads();
        if (w < 4) {
#pragma unroll
            for (int j = 0; j < 2; ++j) {
                float ts = redS[(0*2+j)*16+lrow] + redS[(1*2+j)*16+lrow] + redS[(2*2+j)*16+lrow] + redS[(3*2+j)*16+lrow];
                float tq = redQ[(0*2+j)*16+lrow] + redQ[(1*2+j)*16+lrow] + redQ[(2*2+j)*16+lrow] + redQ[(3*2+j)*16+lrow];
                float mn = ts * (1.f / 64.f);
                float vr = tq * (1.f / 64.f) - mn * mn;
                int n = n0 + j * 16 + lrow;
                float inv = rsqrtf(vr + 1e-5f) * gamma[n];
                float bet = beta[n];
#pragma unroll
                for (int r = 0; r < 4; ++r) {
                    int m = w * 16 + lq * 4 + r;
                    float sv = fmaxf((v[j][r] - mn) * inv + bet, 0.f);
                    out_f32[(size_t)m * F + n] = sv;
                    out_bf[(size_t)m * F + n] = f2bf(sv);
                }
            }
        }
    } else {
        if (w < 4) {
#pragma unroll
            for (int j = 0; j < 2; ++j)
#pragma unroll
                for (int r = 0; r < 4; ++r) {
                    int m = w * 16 + lq * 4 + r;
                    int n = n0 + j * 16 + lrow;
                    size_t o = (size_t)m * F + n;
                    float ov = base_f32[o] + scale * (s_in[o] + acc[j][r]);
                    out_f32[o] = ov;
                    out_bf[o] = f2bf(ov);
                }
        }
    }
}

// ---------------- f32 -> bf16 convert ----------------
__global__ __launch_bounds__(256) void cvt_bf(const float* __restrict__ in, ushort_t* __restrict__ out) {
    size_t i = ((size_t)blockIdx.x * 256 + threadIdx.x) * 4;
    float4 v = *reinterpret_cast<const float4*>(in + i);
    ushort_t p[4] = { f2bf(v.x), f2bf(v.y), f2bf(v.z), f2bf(v.w) };
    *reinterpret_cast<uint2*>(out + i) = *reinterpret_cast<uint2*>(p);
}

// ---------------- coefficient transpose for H-solve ----------------
__global__ __launch_bounds__(256) void transpose_coeff(
    const float* __restrict__ b1, const float* __restrict__ t1,
    const float* __restrict__ b2, const float* __restrict__ t2,
    float* __restrict__ o) {
    int idx = blockIdx.x * 256 + threadIdx.x;
    if (idx >= 4 * 6912) return;
    int a = idx / 6912, rem = idx % 6912;
    int c = rem / 2304, r2 = rem % 2304, wq = r2 / 48, k = r2 % 48;
    const float* src = (a == 0) ? b1 : (a == 1) ? t1 : (a == 2) ? b2 : t2;
    o[idx] = src[c * 2304 + k * 48 + wq];
}

// ---------------- diffusion (ADI, register-resident Thomas) ----------------
__device__ __forceinline__ void thomas_row(float* up, int stride,
                                           const float* __restrict__ cb,
                                           const float* __restrict__ ct,
                                           float tcur, float dt2) {
    float cov[48], ur[48];
#pragma unroll
    for (int k = 0; k < 48; ++k)
        cov[k] = fminf(fmaxf(cb[k] + ct[k] * tcur, 1e-6f), 10.f) * dt2;
#pragma unroll
    for (int k = 0; k < 48; ++k) ur[k] = up[k * stride];
    float cp = 0.f, dp = 0.f;
#pragma unroll
    for (int k = 0; k < 48; ++k) {
        float co = cov[k];
        float bd = (k == 0 || k == 47) ? (1.f + co) : (1.f + 2.f * co);
        float den = bd + co * cp + 1e-6f;
        float rin = __builtin_amdgcn_rcpf(den);
        float cs = -co * rin;
        float ds = (ur[k] + co * dp) * rin;
        cov[k] = cs; ur[k] = ds; cp = cs; dp = ds;
    }
    float xv = ur[47];
#pragma unroll
    for (int k = 46; k >= 0; --k) { xv = ur[k] - cov[k] * xv; ur[k] = xv; }
#pragma unroll
    for (int k = 0; k < 48; ++k) up[k * stride] = ur[k];
}

__global__ __launch_bounds__(192) void diffusion_kern(
    const float* __restrict__ x,
    const float* __restrict__ ab1, const float* __restrict__ atc1,
    const float* __restrict__ ab2, const float* __restrict__ atc2,
    const float* __restrict__ btr,
    const float* __restrict__ mix1, const float* __restrict__ mix2,
    float* __restrict__ out1, float* __restrict__ out2)
{
    int blk = blockIdx.x;
    bool second = blk >= 64;
    int b = blk & 63;
    const float* ab  = second ? ab2  : ab1;
    const float* atc = second ? atc2 : atc1;
    const float* bbT = btr + (second ? 13824 : 0);
    const float* btT = btr + (second ? 20736 : 6912);
    const float* mx  = second ? mix2 : mix1;
    float dt = second ? 0.002f : 0.001f;
    int nsteps = second ? 5 : 8;
    float* out = second ? out2 : out1;

    __shared__ float u[3][48][49];
    int t = threadIdx.x;
    for (int idx = t; idx < 6912; idx += 192) {
        int c = idx / 2304, rem = idx % 2304;
        u[c][rem / 48][rem % 48] = x[(size_t)b * 6912 + idx];
    }
    float m00 = mx[0], m01 = mx[1], m02 = mx[2];
    float m10 = mx[3], m11 = mx[4], m12 = mx[5];
    float m20 = mx[6], m21 = mx[7], m22 = mx[8];
    __syncthreads();
    float tcur = 0.f, dt2 = dt * 0.5f;
    int cc = t / 48, rc = t % 48;
    for (int step = 0; step < nsteps; ++step) {
        float v0[12], v1[12], v2[12];
#pragma unroll
        for (int j = 0; j < 12; ++j) {
            int p = t + j * 192;
            int h = p / 48, wq = p % 48;
            v0[j] = u[0][h][wq]; v1[j] = u[1][h][wq]; v2[j] = u[2][h][wq];
        }
        __syncthreads();
#pragma unroll
        for (int j = 0; j < 12; ++j) {
            int p = t + j * 192;
            int h = p / 48, wq = p % 48;
            u[0][h][wq] = m00 * v0[j] + m01 * v1[j] + m02 * v2[j];
            u[1][h][wq] = m10 * v0[j] + m11 * v1[j] + m12 * v2[j];
            u[2][h][wq] = m20 * v0[j] + m21 * v1[j] + m22 * v2[j];
        }
        __syncthreads();
        if (t < 144)
            thomas_row(&u[cc][rc][0], 1, ab + (cc * 48 + rc) * 48, atc + (cc * 48 + rc) * 48, tcur, dt2);
        __syncthreads();
        tcur += dt2;
        if (t < 144)
            thomas_row(&u[cc][0][rc], 49, bbT + (cc * 48 + rc) * 48, btT + (cc * 48 + rc) * 48, tcur, dt2);
        __syncthreads();
        tcur += dt2;
    }
    for (int idx = t; idx < 6912; idx += 192) {
        int c = idx / 2304, rem = idx % 2304;
        out[(size_t)b * 6912 + idx] = u[c][rem / 48][rem % 48];
    }
}

// ---------------- combine + final per-channel BN ----------------
__global__ __launch_bounds__(256) void combine_pass1(
    const float* __restrict__ cw,
    const float* __restrict__ d1, const float* __restrict__ d2,
    const float* __restrict__ yp, const float* __restrict__ yh,
    float* __restrict__ comb, float* __restrict__ stats)
{
    float c0 = cw[0], c1 = cw[1], c2 = cw[2], c3 = cw[3];
    float mxv = fmaxf(fmaxf(c0, c1), fmaxf(c2, c3));
    float e0 = expf(c0 - mxv), e1 = expf(c1 - mxv), e2 = expf(c2 - mxv), e3 = expf(c3 - mxv);
    float es = e0 + e1 + e2 + e3;
    float w0 = e0 / es, w1 = e1 / es, w2 = e2 / es, w3 = e3 / es;
    size_t base = (size_t)blockIdx.x * 1024;
    float ls[3] = {0.f, 0.f, 0.f}, lq[3] = {0.f, 0.f, 0.f};
#pragma unroll
    for (int j = 0; j < 4; ++j) {
        size_t idx = base + threadIdx.x + j * 256;
        float v = w0 * d1[idx] + w1 * d2[idx] + w2 * yp[idx] + w3 * yh[idx];
        comb[idx] = v;
        int c = (int)((idx / 2304) % 3);
        if (c == 0)      { ls[0] += v; lq[0] += v * v; }
        else if (c == 1) { ls[1] += v; lq[1] += v * v; }
        else             { ls[2] += v; lq[2] += v * v; }
    }
    __shared__ float bsum[6];
    if (threadIdx.x < 6) bsum[threadIdx.x] = 0.f;
    __syncthreads();
#pragma unroll
    for (int c = 0; c < 3; ++c) {
        atomicAdd(&bsum[c], ls[c]);
        atomicAdd(&bsum[3 + c], lq[c]);
    }
    __syncthreads();
    if (threadIdx.x < 6) atomicAdd(&stats[threadIdx.x], bsum[threadIdx.x]);
}

__global__ __launch_bounds__(256) void combine_pass2(
    const float* __restrict__ comb, const float* __restrict__ stats,
    const float* __restrict__ fng, const float* __restrict__ fnb,
    float* __restrict__ out0)
{
    const float inv_n = 1.f / 147456.f;
    size_t base = (size_t)blockIdx.x * 1024;
#pragma unroll
    for (int j = 0; j < 4; ++j) {
        size_t idx = base + threadIdx.x + j * 256;
        int c = (int)((idx / 2304) % 3);
        float mean = stats[c] * inv_n;
        float var = stats[3 + c] * inv_n - mean * mean;
        out0[idx] = (comb[idx] - mean) * rsqrtf(var + 1e-5f) * fng[c] + fnb[c];
    }
}

// ---------------- workspace ----------------
static constexpr size_t EB  = (size_t)F * F * 2;   // one bf16 panel matrix
static constexpr size_t NF4 = NF * 4;              // one f32 activation buffer
static constexpr size_t WS_NEED = 6 * EB + 14 * NF4 + 4 * (NF * 2) + (1 << 20);

static void* g_ws = nullptr;
namespace {
struct WsInit {
    WsInit() { if (hipMalloc(&g_ws, WS_NEED) != hipSuccess) g_ws = nullptr; }
};
WsInit g_wsinit;
}

// ---------------- launch ----------------
extern "C" void kernel_launch(void* const* d_in, const int* in_sizes, int n_in,
                              void* d_out, int out_size, void* d_ws, size_t ws_size,
                              hipStream_t stream)
{
    const float* x    = (const float*)d_in[0];
    const float* ab1  = (const float*)d_in[1];
    const float* bb1  = (const float*)d_in[2];
    const float* atc1 = (const float*)d_in[3];
    const float* btc1 = (const float*)d_in[4];
    const float* mix1 = (const float*)d_in[5];
    const float* ab2  = (const float*)d_in[6];
    const float* bb2  = (const float*)d_in[7];
    const float* atc2 = (const float*)d_in[8];
    const float* btc2 = (const float*)d_in[9];
    const float* mix2 = (const float*)d_in[10];
    const float* Kp   = (const float*)d_in[11];
    const float* gp   = (const float*)d_in[12];
    const float* bp   = (const float*)d_in[13];
    const float* Ky   = (const float*)d_in[14];
    const float* gy   = (const float*)d_in[15];
    const float* by_  = (const float*)d_in[16];
    const float* Kz   = (const float*)d_in[17];
    const float* gz   = (const float*)d_in[18];
    const float* bz   = (const float*)d_in[19];
    const float* cw   = (const float*)d_in[20];
    const float* fng  = (const float*)d_in[21];
    const float* fnb  = (const float*)d_in[22];

    float* out   = (float*)d_out;
    float* o_cmb = out;
    float* o_d1  = out + NF;
    float* o_d2  = out + 2 * NF;
    float* o_yp  = out + 3 * NF;
    float* o_yh  = out + 4 * NF;

    char* wsb = (ws_size >= WS_NEED) ? (char*)d_ws : (char*)g_ws;
    if (!wsb) wsb = (char*)d_ws;

    char* p = wsb;
    auto bump = [&](size_t bytes) { char* r = p; p += (bytes + 255) & ~(size_t)255; return r; };
    ushort_t* P1p = (ushort_t*)bump(EB);
    ushort_t* P2p = (ushort_t*)bump(EB);
    ushort_t* P1y = (ushort_t*)bump(EB);
    ushort_t* P2y = (ushort_t*)bump(EB);
    ushort_t* P1z = (ushort_t*)bump(EB);
    ushort_t* P2z = (ushort_t*)bump(EB);
    float* sbuf_p = (float*)bump(NF4);
    float* sbuf_h = (float*)bump(NF4);
    ushort_t* sbf_p = (ushort_t*)bump(NF * 2);
    ushort_t* sbf_h = (ushort_t*)bump(NF * 2);
    ushort_t* Abf_p = (ushort_t*)bump(NF * 2);
    ushort_t* Abf_h = (ushort_t*)bump(NF * 2);
    float* Z0f  = (float*)bump(NF4);
    float* Y1   = (float*)bump(NF4);
    float* Y2   = (float*)bump(NF4);
    float* Y3   = (float*)bump(NF4);
    float* Yh1  = (float*)bump(NF4);
    float* Z1   = (float*)bump(NF4);
    float* Yh2  = (float*)bump(NF4);
    float* Z2   = (float*)bump(NF4);
    float* comb = (float*)bump(NF4);
    float* stats = (float*)bump(256);
    float* btr   = (float*)bump(4 * 6912 * 4);

    hipMemsetAsync(stats, 0, 32, stream);
    hipMemsetAsync(Z0f, 0, NF4, stream);
    hipMemsetAsync(Abf_h, 0, NF * 2, stream);

    transpose_coeff<<<108, 256, 0, stream>>>(bb1, btc1, bb2, btc2, btr);
    diffusion_kern<<<128, 192, 0, stream>>>(x, ab1, atc1, ab2, atc2, btr, mix1, mix2, o_d1, o_d2);

    build_ep3<<<dim3(108, 108, 3), 256, 0, stream>>>(Kp, Ky, Kz, P1p, P2p, P1y, P2y, P1z, P2z);

    cvt_bf<<<432, 256, 0, stream>>>(x, Abf_p);

    // merged step: P-chain (slot 0) || H-chain (slot 1)
    auto step2 = [&](const float* A1p, const float* Obp, float* Onp,          // P: A1, Obase, Onew
                     const ushort_t* P1h, const ushort_t* P2h,                // H: panels
                     const float* gh, const float* bth,                       // H: bn params
                     const float* A1h, const float* Obh, float* Onh) {        // H: A1, Obase, Onew
        gemm_fused<0><<<dim3(NT2, 2), 512, GEMM_LDS, stream>>>(
            Abf_p, P1p, A1p, nullptr, gp, bp, 0.f, sbuf_p, sbf_p,
            Abf_h, P1h, A1h, nullptr, gh, bth, 0.f, sbuf_h, sbf_h);
        gemm_fused<1><<<dim3(NT2, 2), 512, GEMM_LDS, stream>>>(
            sbf_p, P2p, Obp, sbuf_p, nullptr, nullptr, -0.5f, Onp, Abf_p,
            sbf_h, P2h, Obh, sbuf_h, nullptr, nullptr, 0.8f, Onh, Abf_h);
    };

    // steps 1-4: P-syms 1-4 || H-syms 1-4
    step2(x,  x,  Y1,   P1y, P2y, gy, by_, Z0f, x,   Yh1);
    step2(Y1, Y1, Y2,   P1z, P2z, gz, bz,  Yh1, Z0f, Z1);
    step2(Y2, Y2, Y3,   P1y, P2y, gy, by_, Z1,  Yh1, Yh2);
    step2(Y3, Y3, o_yp, P1z, P2z, gz, bz,  Yh2, Z1,  Z2);

    // step 5: H-sym 5 only
    gemm_fused<0><<<dim3(NT2, 1), 512, GEMM_LDS, stream>>>(
        Abf_h, P1y, Z2, nullptr, gy, by_, 0.f, sbuf_h, sbf_h,
        nullptr, nullptr, nullptr, nullptr, nullptr, nullptr, 0.f, nullptr, nullptr);
    gemm_fused<1><<<dim3(NT2, 1), 512, GEMM_LDS, stream>>>(
        sbf_h, P2y, Yh2, sbuf_h, nullptr, nullptr, 0.8f, o_yh, Abf_h,
        nullptr, nullptr, nullptr, nullptr, nullptr, nullptr, 0.f, nullptr, nullptr);

    combine_pass1<<<432, 256, 0, stream>>>(cw, o_d1, o_d2, o_yp, o_yh, comb, stats);
    combine_pass2<<<432, 256, 0, stream>>>(comb, stats, fng, fnb, o_cmb);
}

// Round 13
// 746.454 us; speedup vs baseline: 1.0827x; 1.0827x over previous
//
#include <hip/hip_runtime.h>
#include <cstdint>
#include <cstddef>

// ---------------- constants ----------------
static constexpr int F      = 6912;          // C*S*S
static constexpr int BATCH  = 64;
static constexpr size_t NF  = (size_t)BATCH * F;   // 442368
static constexpr int BKT    = 64;            // k per LDS stage
static constexpr int NT     = F / BKT;       // 108 k-stages total
static constexpr int NTH    = NT / 2;        // 54 per wave-group
static constexpr int NT2    = F / 32;        // 216 n-tiles (n=32)
static constexpr int DEPTH  = 6;             // LDS ring buffers per group (= PREF+2)
static constexpr int PREF   = 4;             // stages prefetched ahead
static constexpr int STAGE_B = 12288;        // bytes per stage: A 8KB + B 4KB
static constexpr int STAGE_U = STAGE_B / 2;  // in ushorts
static constexpr size_t GEMM_LDS = 2 * (size_t)DEPTH * STAGE_B + 1024;  // 148480

typedef short bf16x8 __attribute__((ext_vector_type(8)));
typedef float f32x4  __attribute__((ext_vector_type(4)));
typedef unsigned short ushort_t;

__device__ __forceinline__ unsigned short f2bf(float f) {
    union { float f; uint32_t u; } x; x.f = f;
    uint32_t r = x.u + 0x7fffu + ((x.u >> 16) & 1u);
    return (unsigned short)(r >> 16);
}

#define GLOAD_LDS16(gp, lp) \
    __builtin_amdgcn_global_load_lds((const __attribute__((address_space(1))) void*)(gp), \
                                     (__attribute__((address_space(3))) void*)(lp), 16, 0, 0)

// ---------------- panel layout ----------------
// EP[((nt*108 + k0t)*32 + n%32)*64 + k%64] (bf16); one (nt,k0t) chunk = 4KB contiguous.
// EP1(n,k) = E[n][k]; EP2(n,k) = E[k][n].

// ---------------- build: K -> EP1, EP2 (E = K - I, bf16) ----------------
__global__ __launch_bounds__(256) void build_ep3(
    const float* __restrict__ K0, const float* __restrict__ K1, const float* __restrict__ K2,
    ushort_t* __restrict__ P10, ushort_t* __restrict__ P20,
    ushort_t* __restrict__ P11, ushort_t* __restrict__ P21,
    ushort_t* __restrict__ P12, ushort_t* __restrict__ P22) {
    __shared__ float tile[64][65];
    int z = blockIdx.z;
    const float* K = (z == 0) ? K0 : (z == 1) ? K1 : K2;
    ushort_t* P1 = (z == 0) ? P10 : (z == 1) ? P11 : P12;
    ushort_t* P2 = (z == 0) ? P20 : (z == 1) ? P21 : P22;
    int bj = blockIdx.x * 64;       // col tile (fast dim -> streaming reads)
    int bi = blockIdx.y * 64;       // row tile
    int t = threadIdx.x;
    int r = t >> 2, c0 = (t & 3) * 16;
    const float4* src = reinterpret_cast<const float4*>(K + (size_t)(bi + r) * F + bj + c0);
    float4 v0 = src[0], v1 = src[1], v2 = src[2], v3 = src[3];
    float vv[16] = {v0.x,v0.y,v0.z,v0.w, v1.x,v1.y,v1.z,v1.w,
                    v2.x,v2.y,v2.z,v2.w, v3.x,v3.y,v3.z,v3.w};
#pragma unroll
    for (int e = 0; e < 16; ++e) {
        float f = vv[e];
        if (bi + r == bj + c0 + e) f -= 1.0f;
        tile[r][c0 + e] = f;
    }
    __syncthreads();
    // EP1: n = bi+rq, k = bj + c8*8+e
#pragma unroll
    for (int i = 0; i < 2; ++i) {
        int g = t + i * 256;
        int rq = g >> 3, c8 = g & 7;
        ushort_t pk[8];
#pragma unroll
        for (int e = 0; e < 8; ++e) pk[e] = f2bf(tile[rq][c8 * 8 + e]);
        size_t nt = (size_t)((bi + rq) >> 5);
        size_t dst = ((nt * 108 + (bj >> 6)) * 32 + (rq & 31)) * 64 + c8 * 8;
        *reinterpret_cast<uint4*>(P1 + dst) = *reinterpret_cast<uint4*>(pk);
    }
    // EP2: n = bj+rq, k = bi + c8*8+e  (transposed LDS read)
#pragma unroll
    for (int i = 0; i < 2; ++i) {
        int g = t + i * 256;
        int rq = g >> 3, c8 = g & 7;
        ushort_t pk[8];
#pragma unroll
        for (int e = 0; e < 8; ++e) pk[e] = f2bf(tile[c8 * 8 + e][rq]);
        size_t nt = (size_t)((bj + rq) >> 5);
        size_t dst = ((nt * 108 + (bi >> 6)) * 32 + (rq & 31)) * 64 + c8 * 8;
        *reinterpret_cast<uint4*>(P2 + dst) = *reinterpret_cast<uint4*>(pk);
    }
}

// ---------------- fused skinny GEMM (M=64, n-tile=32, 512 thr, in-block K-split) ----------
__device__ __forceinline__ void issue_stage(const ushort_t* __restrict__ Abf,
                                            const ushort_t* __restrict__ EP,
                                            ushort_t* ring, int sidx,
                                            int nt_blk, int kt, int wl, int l) {
    int k0 = kt * BKT;
    ushort_t* bufA = ring + sidx * STAGE_U;
    ushort_t* bufB = bufA + 4096;
    // A: 64 rows x 64 k bf16, XOR-swizzled granules (2 issues/thread)
#pragma unroll
    for (int i = 0; i < 2; ++i) {
        int slot = wl * 128 + i * 64 + l;
        int row = slot >> 3;
        int cs16 = (slot & 7) ^ (row & 7);
        GLOAD_LDS16(Abf + (size_t)row * F + k0 + cs16 * 8, bufA + (wl * 128 + i * 64) * 8);
    }
    // B: one 4KB contiguous panel chunk; XOR swizzle folded into source offset
    {
        const ushort_t* bbase = EP + ((size_t)nt_blk * 108 + kt) * 2048;
        int slot = wl * 64 + l;
        int row = slot >> 3;
        int cs16 = (slot & 7) ^ (row & 7);
        GLOAD_LDS16(bbase + row * 64 + cs16 * 8, bufB + (wl * 64) * 8);
    }
}

__device__ __forceinline__ void compute_stage(const ushort_t* ring, int sidx,
                                              f32x4 acc[2], int wl, int l) {
    const char* base = (const char*)(ring + sidx * STAGE_U);
    int lrow = l & 15, lq = l >> 4;
    int arow = wl * 16 + lrow;
#pragma unroll
    for (int ks = 0; ks < 2; ++ks) {
        int acol = ((ks * 4 + lq) ^ (arow & 7)) * 16;
        bf16x8 af = *(const bf16x8*)(base + arow * 128 + acol);
#pragma unroll
        for (int j = 0; j < 2; ++j) {
            int brow = j * 16 + lrow;
            int bcol = ((ks * 4 + lq) ^ (brow & 7)) * 16;
            bf16x8 bf = *(const bf16x8*)(base + 8192 + brow * 128 + bcol);
            acc[j] = __builtin_amdgcn_mfma_f32_16x16x32_bf16(af, bf, acc[j], 0, 0, 0);
        }
    }
}

template<int MODE>
__global__ __launch_bounds__(512) void gemm_fused(
    const ushort_t* __restrict__ Abf, const ushort_t* __restrict__ EP,
    const float* __restrict__ base_f32,   // MODE0: A1 (identity term); MODE1: Obase
    const float* __restrict__ s_in,       // MODE1 only
    const float* __restrict__ gamma, const float* __restrict__ beta,
    float scale,
    float* __restrict__ out_f32, ushort_t* __restrict__ out_bf)
{
    extern __shared__ __align__(16) char smem[];
    ushort_t* stage = (ushort_t*)smem;                                 // 2 rings
    float* redS = (float*)(smem + 2 * DEPTH * STAGE_B);
    float* redQ = redS + 128;

    int nt_blk = blockIdx.x;
    int n0 = nt_blk * 32;
    int tid = threadIdx.x;
    int w = tid >> 6, l = tid & 63;
    int wl = w & 3;                 // wave within group
    int g  = w >> 2;                // k-group 0/1
    ushort_t* ring = stage + g * (DEPTH * STAGE_U);
    int kbase = g * NTH;

    f32x4 acc[2];
    acc[0] = (f32x4)0.0f; acc[1] = (f32x4)0.0f;

#pragma unroll
    for (int t = 0; t < PREF; ++t) issue_stage(Abf, EP, ring, t, nt_blk, kbase + t, wl, l);

    for (int t = 0; t < NTH; ++t) {
        if (t + PREF < NTH) issue_stage(Abf, EP, ring, (t + PREF) % DEPTH, nt_blk, kbase + t + PREF, wl, l);
        int ahead = NTH - 1 - t; if (ahead > PREF) ahead = PREF;
        if (ahead >= 4)      asm volatile("s_waitcnt vmcnt(12)" ::: "memory");
        else if (ahead == 3) asm volatile("s_waitcnt vmcnt(9)"  ::: "memory");
        else if (ahead == 2) asm volatile("s_waitcnt vmcnt(6)"  ::: "memory");
        else if (ahead == 1) asm volatile("s_waitcnt vmcnt(3)"  ::: "memory");
        else                 asm volatile("s_waitcnt vmcnt(0)"  ::: "memory");
        __builtin_amdgcn_s_barrier();
        asm volatile("" ::: "memory");
        compute_stage(ring, t % DEPTH, acc, wl, l);
    }

    // ---- cross-group K reduction (group 1 -> group 0) via reused ring LDS ----
    __syncthreads();
    float* accx = (float*)smem;
    if (w >= 4) {
        int base = ((w - 4) * 64 + l) * 8;
#pragma unroll
        for (int r = 0; r < 4; ++r) { accx[base + r] = acc[0][r]; accx[base + 4 + r] = acc[1][r]; }
    }
    __syncthreads();
    if (w < 4) {
        int base = (w * 64 + l) * 8;
#pragma unroll
        for (int r = 0; r < 4; ++r) { acc[0][r] += accx[base + r]; acc[1][r] += accx[base + 4 + r]; }
    }

    int lrow = l & 15, lq = l >> 4;
    if (MODE == 0) {
        float v[2][4];
        if (w < 4) {
#pragma unroll
            for (int j = 0; j < 2; ++j)
#pragma unroll
                for (int r = 0; r < 4; ++r) {
                    int m = w * 16 + lq * 4 + r;
                    int n = n0 + j * 16 + lrow;
                    v[j][r] = acc[j][r] + base_f32[(size_t)m * F + n];
                }
#pragma unroll
            for (int j = 0; j < 2; ++j) {
                float ps = v[j][0] + v[j][1] + v[j][2] + v[j][3];
                float pq = v[j][0]*v[j][0] + v[j][1]*v[j][1] + v[j][2]*v[j][2] + v[j][3]*v[j][3];
                ps += __shfl_xor(ps, 16); pq += __shfl_xor(pq, 16);
                ps += __shfl_xor(ps, 32); pq += __shfl_xor(pq, 32);
                if (lq == 0) { redS[(w * 2 + j) * 16 + lrow] = ps; redQ[(w * 2 + j) * 16 + lrow] = pq; }
            }
        }
        __syncthreads();
        if (w < 4) {
#pragma unroll
            for (int j = 0; j < 2; ++j) {
                float ts = redS[(0*2+j)*16+lrow] + redS[(1*2+j)*16+lrow] + redS[(2*2+j)*16+lrow] + redS[(3*2+j)*16+lrow];
                float tq = redQ[(0*2+j)*16+lrow] + redQ[(1*2+j)*16+lrow] + redQ[(2*2+j)*16+lrow] + redQ[(3*2+j)*16+lrow];
                float mn = ts * (1.f / 64.f);
                float vr = tq * (1.f / 64.f) - mn * mn;
                int n = n0 + j * 16 + lrow;
                float inv = rsqrtf(vr + 1e-5f) * gamma[n];
                float bet = beta[n];
#pragma unroll
                for (int r = 0; r < 4; ++r) {
                    int m = w * 16 + lq * 4 + r;
                    float sv = fmaxf((v[j][r] - mn) * inv + bet, 0.f);
                    out_f32[(size_t)m * F + n] = sv;
                    out_bf[(size_t)m * F + n] = f2bf(sv);
                }
            }
        }
    } else {
        if (w < 4) {
#pragma unroll
            for (int j = 0; j < 2; ++j)
#pragma unroll
                for (int r = 0; r < 4; ++r) {
                    int m = w * 16 + lq * 4 + r;
                    int n = n0 + j * 16 + lrow;
                    size_t o = (size_t)m * F + n;
                    float ov = base_f32[o] + scale * (s_in[o] + acc[j][r]);
                    out_f32[o] = ov;
                    out_bf[o] = f2bf(ov);
                }
        }
    }
}

// ---------------- H-step-1 shortcut: Zh0 = 0 (algorithmic) => s = relu(by_) broadcast ----
__global__ __launch_bounds__(256) void ep_bcast(
    const float* __restrict__ beta_, float* __restrict__ s_out, ushort_t* __restrict__ s_bf)
{
    size_t idx = ((size_t)blockIdx.x * 256 + threadIdx.x) * 4;
    unsigned i0 = (unsigned)(idx % F);
    float4 b = *reinterpret_cast<const float4*>(beta_ + i0);
    float4 sv;
    sv.x = fmaxf(b.x, 0.f); sv.y = fmaxf(b.y, 0.f);
    sv.z = fmaxf(b.z, 0.f); sv.w = fmaxf(b.w, 0.f);
    *reinterpret_cast<float4*>(s_out + idx) = sv;
    ushort_t pk[4] = { f2bf(sv.x), f2bf(sv.y), f2bf(sv.z), f2bf(sv.w) };
    *reinterpret_cast<uint2*>(s_bf + idx) = *reinterpret_cast<uint2*>(pk);
}

// ---------------- f32 -> bf16 convert ----------------
__global__ __launch_bounds__(256) void cvt_bf(const float* __restrict__ in, ushort_t* __restrict__ out) {
    size_t i = ((size_t)blockIdx.x * 256 + threadIdx.x) * 4;
    float4 v = *reinterpret_cast<const float4*>(in + i);
    ushort_t p[4] = { f2bf(v.x), f2bf(v.y), f2bf(v.z), f2bf(v.w) };
    *reinterpret_cast<uint2*>(out + i) = *reinterpret_cast<uint2*>(p);
}

// ---------------- coefficient transpose for H-solve ----------------
__global__ __launch_bounds__(256) void transpose_coeff(
    const float* __restrict__ b1, const float* __restrict__ t1,
    const float* __restrict__ b2, const float* __restrict__ t2,
    float* __restrict__ o) {
    int idx = blockIdx.x * 256 + threadIdx.x;
    if (idx >= 4 * 6912) return;
    int a = idx / 6912, rem = idx % 6912;
    int c = rem / 2304, r2 = rem % 2304, wq = r2 / 48, k = r2 % 48;
    const float* src = (a == 0) ? b1 : (a == 1) ? t1 : (a == 2) ? b2 : t2;
    o[idx] = src[c * 2304 + k * 48 + wq];
}

// ---------------- diffusion (ADI, register-resident Thomas) ----------------
__device__ __forceinline__ void thomas_row(float* up, int stride,
                                           const float* __restrict__ cb,
                                           const float* __restrict__ ct,
                                           float tcur, float dt2) {
    float cov[48], ur[48];
#pragma unroll
    for (int k = 0; k < 48; ++k)
        cov[k] = fminf(fmaxf(cb[k] + ct[k] * tcur, 1e-6f), 10.f) * dt2;
#pragma unroll
    for (int k = 0; k < 48; ++k) ur[k] = up[k * stride];
    float cp = 0.f, dp = 0.f;
#pragma unroll
    for (int k = 0; k < 48; ++k) {
        float co = cov[k];
        float bd = (k == 0 || k == 47) ? (1.f + co) : (1.f + 2.f * co);
        float den = bd + co * cp + 1e-6f;
        float rin = __builtin_amdgcn_rcpf(den);
        float cs = -co * rin;
        float ds = (ur[k] + co * dp) * rin;
        cov[k] = cs; ur[k] = ds; cp = cs; dp = ds;
    }
    float xv = ur[47];
#pragma unroll
    for (int k = 46; k >= 0; --k) { xv = ur[k] - cov[k] * xv; ur[k] = xv; }
#pragma unroll
    for (int k = 0; k < 48; ++k) up[k * stride] = ur[k];
}

__global__ __launch_bounds__(192) void diffusion_kern(
    const float* __restrict__ x,
    const float* __restrict__ ab1, const float* __restrict__ atc1,
    const float* __restrict__ ab2, const float* __restrict__ atc2,
    const float* __restrict__ btr,
    const float* __restrict__ mix1, const float* __restrict__ mix2,
    float* __restrict__ out1, float* __restrict__ out2)
{
    int blk = blockIdx.x;
    bool second = blk >= 64;
    int b = blk & 63;
    const float* ab  = second ? ab2  : ab1;
    const float* atc = second ? atc2 : atc1;
    const float* bbT = btr + (second ? 13824 : 0);
    const float* btT = btr + (second ? 20736 : 6912);
    const float* mx  = second ? mix2 : mix1;
    float dt = second ? 0.002f : 0.001f;
    int nsteps = second ? 5 : 8;
    float* out = second ? out2 : out1;

    __shared__ float u[3][48][49];
    int t = threadIdx.x;
    for (int idx = t; idx < 6912; idx += 192) {
        int c = idx / 2304, rem = idx % 2304;
        u[c][rem / 48][rem % 48] = x[(size_t)b * 6912 + idx];
    }
    float m00 = mx[0], m01 = mx[1], m02 = mx[2];
    float m10 = mx[3], m11 = mx[4], m12 = mx[5];
    float m20 = mx[6], m21 = mx[7], m22 = mx[8];
    __syncthreads();
    float tcur = 0.f, dt2 = dt * 0.5f;
    int cc = t / 48, rc = t % 48;
    for (int step = 0; step < nsteps; ++step) {
        float v0[12], v1[12], v2[12];
#pragma unroll
        for (int j = 0; j < 12; ++j) {
            int p = t + j * 192;
            int h = p / 48, wq = p % 48;
            v0[j] = u[0][h][wq]; v1[j] = u[1][h][wq]; v2[j] = u[2][h][wq];
        }
        __syncthreads();
#pragma unroll
        for (int j = 0; j < 12; ++j) {
            int p = t + j * 192;
            int h = p / 48, wq = p % 48;
            u[0][h][wq] = m00 * v0[j] + m01 * v1[j] + m02 * v2[j];
            u[1][h][wq] = m10 * v0[j] + m11 * v1[j] + m12 * v2[j];
            u[2][h][wq] = m20 * v0[j] + m21 * v1[j] + m22 * v2[j];
        }
        __syncthreads();
        if (t < 144)
            thomas_row(&u[cc][rc][0], 1, ab + (cc * 48 + rc) * 48, atc + (cc * 48 + rc) * 48, tcur, dt2);
        __syncthreads();
        tcur += dt2;
        if (t < 144)
            thomas_row(&u[cc][0][rc], 49, bbT + (cc * 48 + rc) * 48, btT + (cc * 48 + rc) * 48, tcur, dt2);
        __syncthreads();
        tcur += dt2;
    }
    for (int idx = t; idx < 6912; idx += 192) {
        int c = idx / 2304, rem = idx % 2304;
        out[(size_t)b * 6912 + idx] = u[c][rem / 48][rem % 48];
    }
}

// ---------------- combine + final per-channel BN ----------------
__global__ __launch_bounds__(256) void combine_pass1(
    const float* __restrict__ cw,
    const float* __restrict__ d1, const float* __restrict__ d2,
    const float* __restrict__ yp, const float* __restrict__ yh,
    float* __restrict__ comb, float* __restrict__ stats)
{
    float c0 = cw[0], c1 = cw[1], c2 = cw[2], c3 = cw[3];
    float mxv = fmaxf(fmaxf(c0, c1), fmaxf(c2, c3));
    float e0 = expf(c0 - mxv), e1 = expf(c1 - mxv), e2 = expf(c2 - mxv), e3 = expf(c3 - mxv);
    float es = e0 + e1 + e2 + e3;
    float w0 = e0 / es, w1 = e1 / es, w2 = e2 / es, w3 = e3 / es;
    size_t base = (size_t)blockIdx.x * 1024;
    float ls[3] = {0.f, 0.f, 0.f}, lq[3] = {0.f, 0.f, 0.f};
#pragma unroll
    for (int j = 0; j < 4; ++j) {
        size_t idx = base + threadIdx.x + j * 256;
        float v = w0 * d1[idx] + w1 * d2[idx] + w2 * yp[idx] + w3 * yh[idx];
        comb[idx] = v;
        int c = (int)((idx / 2304) % 3);
        if (c == 0)      { ls[0] += v; lq[0] += v * v; }
        else if (c == 1) { ls[1] += v; lq[1] += v * v; }
        else             { ls[2] += v; lq[2] += v * v; }
    }
    __shared__ float bsum[6];
    if (threadIdx.x < 6) bsum[threadIdx.x] = 0.f;
    __syncthreads();
#pragma unroll
    for (int c = 0; c < 3; ++c) {
        atomicAdd(&bsum[c], ls[c]);
        atomicAdd(&bsum[3 + c], lq[c]);
    }
    __syncthreads();
    if (threadIdx.x < 6) atomicAdd(&stats[threadIdx.x], bsum[threadIdx.x]);
}

__global__ __launch_bounds__(256) void combine_pass2(
    const float* __restrict__ comb, const float* __restrict__ stats,
    const float* __restrict__ fng, const float* __restrict__ fnb,
    float* __restrict__ out0)
{
    const float inv_n = 1.f / 147456.f;
    size_t base = (size_t)blockIdx.x * 1024;
#pragma unroll
    for (int j = 0; j < 4; ++j) {
        size_t idx = base + threadIdx.x + j * 256;
        int c = (int)((idx / 2304) % 3);
        float mean = stats[c] * inv_n;
        float var = stats[3 + c] * inv_n - mean * mean;
        out0[idx] = (comb[idx] - mean) * rsqrtf(var + 1e-5f) * fng[c] + fnb[c];
    }
}

// ---------------- workspace ----------------
static constexpr size_t EB  = (size_t)F * F * 2;   // one bf16 panel matrix
static constexpr size_t NF4 = NF * 4;              // one f32 activation buffer
static constexpr size_t WS_NEED = 6 * EB + 12 * NF4 + 2 * (NF * 2) + (1 << 20);

static void* g_ws = nullptr;
namespace {
struct WsInit {
    WsInit() { if (hipMalloc(&g_ws, WS_NEED) != hipSuccess) g_ws = nullptr; }
};
WsInit g_wsinit;
}

// ---------------- launch ----------------
extern "C" void kernel_launch(void* const* d_in, const int* in_sizes, int n_in,
                              void* d_out, int out_size, void* d_ws, size_t ws_size,
                              hipStream_t stream)
{
    const float* x    = (const float*)d_in[0];
    const float* ab1  = (const float*)d_in[1];
    const float* bb1  = (const float*)d_in[2];
    const float* atc1 = (const float*)d_in[3];
    const float* btc1 = (const float*)d_in[4];
    const float* mix1 = (const float*)d_in[5];
    const float* ab2  = (const float*)d_in[6];
    const float* bb2  = (const float*)d_in[7];
    const float* atc2 = (const float*)d_in[8];
    const float* btc2 = (const float*)d_in[9];
    const float* mix2 = (const float*)d_in[10];
    const float* Kp   = (const float*)d_in[11];
    const float* gp   = (const float*)d_in[12];
    const float* bp   = (const float*)d_in[13];
    const float* Ky   = (const float*)d_in[14];
    const float* gy   = (const float*)d_in[15];
    const float* by_  = (const float*)d_in[16];
    const float* Kz   = (const float*)d_in[17];
    const float* gz   = (const float*)d_in[18];
    const float* bz   = (const float*)d_in[19];
    const float* cw   = (const float*)d_in[20];
    const float* fng  = (const float*)d_in[21];
    const float* fnb  = (const float*)d_in[22];

    float* out   = (float*)d_out;
    float* o_cmb = out;
    float* o_d1  = out + NF;
    float* o_d2  = out + 2 * NF;
    float* o_yp  = out + 3 * NF;
    float* o_yh  = out + 4 * NF;

    char* wsb = (ws_size >= WS_NEED) ? (char*)d_ws : (char*)g_ws;
    if (!wsb) wsb = (char*)d_ws;

    char* p = wsb;
    auto bump = [&](size_t bytes) { char* r = p; p += (bytes + 255) & ~(size_t)255; return r; };
    ushort_t* P1p = (ushort_t*)bump(EB);
    ushort_t* P2p = (ushort_t*)bump(EB);
    ushort_t* P1y = (ushort_t*)bump(EB);
    ushort_t* P2y = (ushort_t*)bump(EB);
    ushort_t* P1z = (ushort_t*)bump(EB);
    ushort_t* P2z = (ushort_t*)bump(EB);
    float* sbuf  = (float*)bump(NF4);
    ushort_t* s_bf = (ushort_t*)bump(NF * 2);
    ushort_t* Abf  = (ushort_t*)bump(NF * 2);
    float* Z0f  = (float*)bump(NF4);
    float* Y1   = (float*)bump(NF4);
    float* Y2   = (float*)bump(NF4);
    float* Y3   = (float*)bump(NF4);
    float* Yh1  = (float*)bump(NF4);
    float* Z1   = (float*)bump(NF4);
    float* Yh2  = (float*)bump(NF4);
    float* Z2   = (float*)bump(NF4);
    float* comb = (float*)bump(NF4);
    float* stats = (float*)bump(256);
    float* btr   = (float*)bump(4 * 6912 * 4);

    hipMemsetAsync(stats, 0, 32, stream);
    hipMemsetAsync(Z0f, 0, NF4, stream);

    transpose_coeff<<<108, 256, 0, stream>>>(bb1, btc1, bb2, btc2, btr);
    diffusion_kern<<<128, 192, 0, stream>>>(x, ab1, atc1, ab2, atc2, btr, mix1, mix2, o_d1, o_d2);

    build_ep3<<<dim3(108, 108, 3), 256, 0, stream>>>(Kp, Ky, Kz, P1p, P2p, P1y, P2y, P1z, P2z);

    cvt_bf<<<432, 256, 0, stream>>>(x, Abf);

    auto sym = [&](const float* A1, const ushort_t* P1, const ushort_t* P2,
                   const float* g, const float* bt, const float* Obase,
                   float sc, float* Onew) {
        gemm_fused<0><<<NT2, 512, GEMM_LDS, stream>>>(Abf, P1, A1, nullptr, g, bt, 0.f, sbuf, s_bf);
        gemm_fused<1><<<NT2, 512, GEMM_LDS, stream>>>(s_bf, P2, Obase, sbuf, nullptr, nullptr, sc, Onew, Abf);
    };

    // Parabolic: Y <- Y + 0.5 * (-(s + s@E))
    sym(x,  P1p, P2p, gp, bp, x,  -0.5f, Y1);
    sym(Y1, P1p, P2p, gp, bp, Y1, -0.5f, Y2);
    sym(Y2, P1p, P2p, gp, bp, Y2, -0.5f, Y3);
    sym(Y3, P1p, P2p, gp, bp, Y3, -0.5f, o_yp);

    // Hamiltonian. Step 1: Zh = 0 (algorithmic) => KY = 0, BN -> beta, s = relu(by_)
    // broadcast over batch — GEMM1 replaced by elementwise broadcast.
    ep_bcast<<<432, 256, 0, stream>>>(by_, sbuf, s_bf);
    gemm_fused<1><<<NT2, 512, GEMM_LDS, stream>>>(s_bf, P2y, x, sbuf, nullptr, nullptr, 0.8f, Yh1, Abf);

    sym(Yh1, P1z, P2z, gz, bz,  Z0f, 0.8f, Z1);
    sym(Z1,  P1y, P2y, gy, by_, Yh1, 0.8f, Yh2);
    sym(Yh2, P1z, P2z, gz, bz,  Z1,  0.8f, Z2);
    sym(Z2,  P1y, P2y, gy, by_, Yh2, 0.8f, o_yh);

    combine_pass1<<<432, 256, 0, stream>>>(cw, o_d1, o_d2, o_yp, o_yh, comb, stats);
    combine_pass2<<<432, 256, 0, stream>>>(comb, stats, fng, fnb, o_cmb);
}